// Round 1
// baseline (1324.066 us; speedup 1.0000x reference)
//
#include <hip/hip_runtime.h>
#include <hip/hip_bf16.h>
#include <cstdint>
#include <cstddef>

typedef unsigned short u16;
typedef __attribute__((ext_vector_type(8))) short short8;
typedef __attribute__((ext_vector_type(4))) float f4;

// ---------- helpers ----------

__device__ __forceinline__ u16 f2bf(float x) {
    union { float f; uint32_t u; } v; v.f = x;
    uint32_t r = v.u + 0x7fffu + ((v.u >> 16) & 1u);   // RNE
    return (u16)(r >> 16);
}

__device__ __forceinline__ void async16(const u16* g, u16* l) {
    __builtin_amdgcn_global_load_lds((__attribute__((address_space(1))) void*)(g),
                                     (__attribute__((address_space(3))) void*)(l),
                                     16, 0, 0);
}

// ---------- bf16 MFMA GEMM:  C[M x BN] = A[M x K] @ W[K x BN] ----------
// A: fp32 row-major (lda = K), converted to bf16 on the fly during LDS staging.
// Bt: pre-converted, pre-tiled weights: [KT][BN][32] bf16 (zero-padded in K).
// C: fp32 row-major (ldc = BN). BN == full N of this GEMM.

template<int BM, int BN, int WM, int WN>
__global__ __launch_bounds__((BM/WM)*(BN/WN)*64)
void gemm_xw(const float* __restrict__ A, const u16* __restrict__ Bt,
             float* __restrict__ C, int M, int K, int KT)
{
    constexpr int WAVES   = (BM/WM)*(BN/WN);
    constexpr int THREADS = WAVES*64;
    constexpr int RF = WM/16, CF = WN/16;
    constexpr int BCH = (BN*64)/(16*THREADS);     // 16B chunks of B per thread
    static_assert((BM*32)/THREADS == 8, "A staging assumes 8 floats per thread");

    __shared__ __align__(16) u16 As[BM*32];
    __shared__ __align__(16) u16 Bs[BN*32];

    const int tid  = threadIdx.x;
    const int wid  = tid >> 6, lane = tid & 63;
    const int quad = lane >> 4, l16 = lane & 15;
    constexpr int WCOLS = BN/WN;
    const int wm = (wid / WCOLS) * WM;
    const int wn = (wid % WCOLS) * WN;
    const long m0 = (long)blockIdx.x * BM;

    const int arow = tid >> 2;            // 4 threads cover one row's 32 k
    const int akk  = (tid & 3) * 8;
    const bool aok = (m0 + arow) < M;
    const float* aptr = A + (size_t)(m0 + arow) * K + akk;

    f4 acc[RF][CF];
    #pragma unroll
    for (int r = 0; r < RF; ++r)
        #pragma unroll
        for (int c = 0; c < CF; ++c)
            #pragma unroll
            for (int g = 0; g < 4; ++g) acc[r][c][g] = 0.f;

    const u16* Asl = As + (wm + l16)*32 + quad*8;
    const u16* Bsl = Bs + (wn + l16)*32 + quad*8;

    for (int kt = 0; kt < KT; ++kt) {
        __syncthreads();
        // stage B (already bf16, tiled contiguously) via async global->LDS DMA
        #pragma unroll
        for (int i = 0; i < BCH; ++i) {
            int c16 = i*THREADS + tid;
            async16(Bt + (size_t)kt*(BN*32) + (size_t)c16*8, (u16*)Bs + c16*8);
        }
        // stage A: fp32 global -> bf16 LDS (predicated: row bound + K tail)
        {
            const int gk = kt*32 + akk;
            f4 v0, v1;
            #pragma unroll
            for (int g = 0; g < 4; ++g) { v0[g] = 0.f; v1[g] = 0.f; }
            if (aok && gk < K) {
                const float* p = aptr + (size_t)kt*32;
                v0 = *(const f4*)p;
                v1 = *(const f4*)(p + 4);
            }
            short8 w;
            #pragma unroll
            for (int g = 0; g < 4; ++g) {
                w[g]   = (short)f2bf(v0[g]);
                w[4+g] = (short)f2bf(v1[g]);
            }
            *(short8*)(As + tid*8) = w;
        }
        __syncthreads();

        short8 af[RF], bfr[CF];
        #pragma unroll
        for (int r = 0; r < RF; ++r) af[r]  = *(const short8*)(Asl + r*16*32);
        #pragma unroll
        for (int c = 0; c < CF; ++c) bfr[c] = *(const short8*)(Bsl + c*16*32);
        #pragma unroll
        for (int r = 0; r < RF; ++r)
            #pragma unroll
            for (int c = 0; c < CF; ++c)
                acc[r][c] = __builtin_amdgcn_mfma_f32_16x16x32_bf16(af[r], bfr[c], acc[r][c], 0, 0, 0);
    }

    // epilogue: D[m=quad*4+g][n=l16] (m89/m91-verified mapping)
    #pragma unroll
    for (int r = 0; r < RF; ++r) {
        const long rb = m0 + wm + r*16 + quad*4;
        #pragma unroll
        for (int c = 0; c < CF; ++c) {
            const int col = wn + c*16 + l16;
            #pragma unroll
            for (int g = 0; g < 4; ++g) {
                long row = rb + g;
                if (row < M) C[row*(long)BN + col] = acc[r][c][g];
            }
        }
    }
}

// ---------- weight prep: W[K x Nn] fp32 -> Bt[KT][Nn][32] bf16, zero-pad K ----------
__global__ void k_prep_w(const float* __restrict__ W, u16* __restrict__ out,
                         int K, int Nn, int total)
{
    int idx = blockIdx.x*256 + threadIdx.x;
    if (idx >= total) return;
    int ki = idx & 31;
    int rest = idx >> 5;
    int nn = rest % Nn;
    int kt = rest / Nn;
    int k = kt*32 + ki;
    float v = (k < K) ? W[(size_t)k*Nn + nn] : 0.f;
    out[idx] = f2bf(v);
}

// ---------- CSR build ----------
__global__ void k_hist(const int* __restrict__ ei, int E, int N, int* counts)
{
    int i = blockIdx.x*256 + threadIdx.x;
    if (i >= E + N) return;
    int d = (i < E) ? ei[E + i] : (i - E);   // self-loop tail
    atomicAdd(&counts[d], 1);
}

__global__ void k_scan1(const int* __restrict__ counts, int* offs, int* partials, int N)
{
    __shared__ int s[256];
    int i = blockIdx.x*256 + threadIdx.x;
    int v = (i < N) ? counts[i] : 0;
    s[threadIdx.x] = v;
    __syncthreads();
    #pragma unroll
    for (int off = 1; off < 256; off <<= 1) {
        int t = (threadIdx.x >= off) ? s[threadIdx.x - off] : 0;
        __syncthreads();
        s[threadIdx.x] += t;
        __syncthreads();
    }
    if (i < N) offs[i + 1] = s[threadIdx.x];     // chunk-local inclusive
    if (threadIdx.x == 255) partials[blockIdx.x] = s[255];
    if (i == 0) offs[0] = 0;
}

__global__ void k_scan2(int* partials, int NB)
{
    __shared__ int s[256];
    int v = (threadIdx.x < NB) ? partials[threadIdx.x] : 0;
    s[threadIdx.x] = v;
    __syncthreads();
    for (int off = 1; off < 256; off <<= 1) {
        int t = (threadIdx.x >= off) ? s[threadIdx.x - off] : 0;
        __syncthreads();
        s[threadIdx.x] += t;
        __syncthreads();
    }
    if (threadIdx.x < NB) partials[threadIdx.x] = s[threadIdx.x] - v;  // exclusive
}

__global__ void k_scan3(int* offs, const int* __restrict__ partials, int N)
{
    int i = blockIdx.x*256 + threadIdx.x;
    if (i < N) offs[i + 1] += partials[blockIdx.x];
}

__global__ void k_copy(const int* __restrict__ a, int* __restrict__ b, int n)
{
    int i = blockIdx.x*256 + threadIdx.x;
    if (i < n) b[i] = a[i];
}

__global__ void k_scatter(const int* __restrict__ ei, int E, int N,
                          int* cursor, int* __restrict__ ssrc)
{
    int i = blockIdx.x*256 + threadIdx.x;
    if (i >= E + N) return;
    int s, d;
    if (i < E) { s = ei[i]; d = ei[E + i]; } else { s = i - E; d = s; }
    int pos = atomicAdd(&cursor[d], 1);
    ssrc[pos] = s;
}

// ---------- attention ----------
// per-node attention logits e_src/e_dst: one wave per node, lane = feature
__global__ void k_scores(const float* __restrict__ h, const float* __restrict__ asrc,
                         const float* __restrict__ adst, float* __restrict__ es,
                         float* __restrict__ ed, int N, int H)
{
    int wave = threadIdx.x >> 6, lane = threadIdx.x & 63;
    int node = blockIdx.x*4 + wave;
    if (node >= N) return;
    const float* row = h + (size_t)node * H * 64;
    for (int hh = 0; hh < H; ++hh) {
        float v = row[hh*64 + lane];
        float s = v * asrc[hh*64 + lane];
        float d = v * adst[hh*64 + lane];
        #pragma unroll
        for (int off = 32; off > 0; off >>= 1) {
            s += __shfl_down(s, off);
            d += __shfl_down(d, off);
        }
        if (lane == 0) { es[node*H + hh] = s; ed[node*H + hh] = d; }
    }
}

// segment-softmax stats: one thread per (node, head)
__global__ void k_stats(const int* __restrict__ offs, const int* __restrict__ ssrc,
                        const float* __restrict__ es, const float* __restrict__ ed,
                        float* __restrict__ mt, float* __restrict__ dt, int N, int H)
{
    int idx = blockIdx.x*blockDim.x + threadIdx.x;
    if (idx >= N*H) return;
    int n = idx / H, hh = idx - n*H;
    int s0 = offs[n], s1 = offs[n + 1];
    float edv = ed[idx];
    float mx = -1e30f;
    for (int j = s0; j < s1; ++j) {
        float e = es[ssrc[j]*H + hh] + edv;
        e = (e > 0.f) ? e : 0.2f*e;
        mx = fmaxf(mx, e);
    }
    float sum = 0.f;
    for (int j = s0; j < s1; ++j) {
        float e = es[ssrc[j]*H + hh] + edv;
        e = (e > 0.f) ? e : 0.2f*e;
        sum += __expf(e - mx);
    }
    mt[idx] = mx; dt[idx] = sum;
}

// aggregation + bias + ELU: block per node, wave per head, lane = feature
__global__ void k_agg(const float* __restrict__ h, const int* __restrict__ offs,
                      const int* __restrict__ ssrc, const float* __restrict__ es,
                      const float* __restrict__ ed, const float* __restrict__ mt,
                      const float* __restrict__ dt, const float* __restrict__ bias,
                      float* __restrict__ out, int N, int H)
{
    int n = blockIdx.x;
    int hh = threadIdx.x >> 6, lane = threadIdx.x & 63;
    int s0 = offs[n], s1 = offs[n + 1];
    int idx = n*H + hh;
    float edv = ed[idx], mx = mt[idx], rden = 1.0f / dt[idx];
    float acc = 0.f;
    const int stride = H*64;
    for (int j = s0; j < s1; ++j) {
        int sidx = ssrc[j];
        float e = es[sidx*H + hh] + edv;
        e = (e > 0.f) ? e : 0.2f*e;
        float alpha = __expf(e - mx) * rden;
        acc += alpha * h[(size_t)sidx*stride + hh*64 + lane];
    }
    float v = acc + bias[hh*64 + lane];
    out[(size_t)n*stride + hh*64 + lane] = (v > 0.f) ? v : (__expf(v) - 1.f);
}

// ---------- classifier: out[N x 3] = h[N x 64] @ Wc[64 x 3] + bc ----------
__global__ void k_classifier(const float* __restrict__ h, const float* __restrict__ Wc,
                             const float* __restrict__ bc, float* __restrict__ out, int N)
{
    __shared__ float wc[192];
    __shared__ float bcs[3];
    if (threadIdx.x < 192) wc[threadIdx.x] = Wc[threadIdx.x];
    if (threadIdx.x < 3)   bcs[threadIdx.x] = bc[threadIdx.x];
    __syncthreads();
    int n = blockIdx.x*blockDim.x + threadIdx.x;
    if (n >= N) return;
    const float4* row = (const float4*)(h + (size_t)n*64);
    float a0 = 0.f, a1 = 0.f, a2 = 0.f;
    #pragma unroll
    for (int q = 0; q < 16; ++q) {
        float4 v = row[q];
        const float* w = &wc[q*12];
        a0 += v.x*w[0] + v.y*w[3] + v.z*w[6] + v.w*w[9];
        a1 += v.x*w[1] + v.y*w[4] + v.z*w[7] + v.w*w[10];
        a2 += v.x*w[2] + v.y*w[5] + v.z*w[8] + v.w*w[11];
    }
    out[n*3 + 0] = a0 + bcs[0];
    out[n*3 + 1] = a1 + bcs[1];
    out[n*3 + 2] = a2 + bcs[2];
}

// ---------- launcher ----------
extern "C" void kernel_launch(void* const* d_in, const int* in_sizes, int n_in,
                              void* d_out, int out_size, void* d_ws, size_t ws_size,
                              hipStream_t stream)
{
    const float* x   = (const float*)d_in[0];
    const float* W1  = (const float*)d_in[1];
    const float* a1s = (const float*)d_in[2];
    const float* a1d = (const float*)d_in[3];
    const float* b1  = (const float*)d_in[4];
    const float* W2  = (const float*)d_in[5];
    const float* a2s = (const float*)d_in[6];
    const float* a2d = (const float*)d_in[7];
    const float* b2  = (const float*)d_in[8];
    const float* W3  = (const float*)d_in[9];
    const float* a3s = (const float*)d_in[10];
    const float* a3d = (const float*)d_in[11];
    const float* b3  = (const float*)d_in[12];
    const float* Wc  = (const float*)d_in[13];
    const float* bc  = (const float*)d_in[14];
    const int*   ei  = (const int*)d_in[15];
    float* out = (float*)d_out;

    const int DIN = in_sizes[1] / 256;    // 5000
    const int N   = in_sizes[0] / DIN;    // 30000
    const int E   = in_sizes[15] / 2;     // 480000
    const int KT1 = (DIN + 31) / 32;      // 157
    const int ET  = E + N;

    char* ws = (char*)d_ws;
    size_t off = 0;
    auto alloc = [&](size_t bytes) -> void* {
        void* p = ws + off;
        off += (bytes + 255) & ~(size_t)255;
        return p;
    };

    float* bufA   = (float*)alloc((size_t)N*256*4);
    float* bufB   = (float*)alloc((size_t)N*256*4);
    u16*  Wt1     = (u16*)alloc((size_t)KT1*256*32*2);
    u16*  Wt2     = (u16*)alloc((size_t)8*256*32*2);
    u16*  Wt3     = (u16*)alloc((size_t)8*64*32*2);
    float* es     = (float*)alloc((size_t)N*4*4);
    float* ed     = (float*)alloc((size_t)N*4*4);
    float* mt     = (float*)alloc((size_t)N*4*4);
    float* dt     = (float*)alloc((size_t)N*4*4);
    int* counts   = (int*)alloc((size_t)N*4);
    int* offs     = (int*)alloc((size_t)(N+1)*4);
    int* cursor   = (int*)alloc((size_t)N*4);
    int* partials = (int*)alloc(1024);
    int* ssrc     = (int*)alloc((size_t)ET*4);

    const int NB = (N + 255)/256;
    const int GM = (N + 63)/64;

    // CSR over (edges + self-loops); graph identical across the 3 layers
    hipMemsetAsync(counts, 0, (size_t)N*4, stream);
    k_hist   <<<(ET+255)/256, 256, 0, stream>>>(ei, E, N, counts);
    k_scan1  <<<NB, 256, 0, stream>>>(counts, offs, partials, N);
    k_scan2  <<<1, 256, 0, stream>>>(partials, NB);
    k_scan3  <<<NB, 256, 0, stream>>>(offs, partials, N);
    k_copy   <<<NB, 256, 0, stream>>>(offs, cursor, N);
    k_scatter<<<(ET+255)/256, 256, 0, stream>>>(ei, E, N, cursor, ssrc);

    // weights -> bf16 tiled
    k_prep_w<<<(KT1*256*32+255)/256, 256, 0, stream>>>(W1, Wt1, DIN, 256, KT1*256*32);
    k_prep_w<<<(8*256*32+255)/256, 256, 0, stream>>>(W2, Wt2, 256, 256, 8*256*32);
    k_prep_w<<<(8*64*32+255)/256, 256, 0, stream>>>(W3, Wt3, 256, 64, 8*64*32);

    // layer 1
    gemm_xw<64,256,64,64><<<GM, 256, 0, stream>>>(x, Wt1, bufA, N, DIN, KT1);
    k_scores<<<(N+3)/4, 256, 0, stream>>>(bufA, a1s, a1d, es, ed, N, 4);
    k_stats <<<(N*4+255)/256, 256, 0, stream>>>(offs, ssrc, es, ed, mt, dt, N, 4);
    k_agg   <<<N, 256, 0, stream>>>(bufA, offs, ssrc, es, ed, mt, dt, b1, bufB, N, 4);
    // layer 2
    gemm_xw<64,256,64,64><<<GM, 256, 0, stream>>>(bufB, Wt2, bufA, N, 256, 8);
    k_scores<<<(N+3)/4, 256, 0, stream>>>(bufA, a2s, a2d, es, ed, N, 4);
    k_stats <<<(N*4+255)/256, 256, 0, stream>>>(offs, ssrc, es, ed, mt, dt, N, 4);
    k_agg   <<<N, 256, 0, stream>>>(bufA, offs, ssrc, es, ed, mt, dt, b2, bufB, N, 4);
    // layer 3 (1 head, mean over 1 head == identity)
    gemm_xw<64,64,16,64><<<GM, 256, 0, stream>>>(bufB, Wt3, bufA, N, 256, 8);
    k_scores<<<(N+3)/4, 256, 0, stream>>>(bufA, a3s, a3d, es, ed, N, 1);
    k_stats <<<(N+255)/256, 256, 0, stream>>>(offs, ssrc, es, ed, mt, dt, N, 1);
    k_agg   <<<N, 64, 0, stream>>>(bufA, offs, ssrc, es, ed, mt, dt, b3, bufB, N, 1);
    // classifier
    k_classifier<<<(N+255)/256, 256, 0, stream>>>(bufB, Wc, bc, out, N);
}

// Round 2
// 1314.891 us; speedup vs baseline: 1.0070x; 1.0070x over previous
//
#include <hip/hip_runtime.h>
#include <hip/hip_bf16.h>
#include <cstdint>
#include <cstddef>

typedef unsigned short u16;
typedef __attribute__((ext_vector_type(8))) short short8;
typedef __attribute__((ext_vector_type(4))) float f4;

// ---------- helpers ----------

__device__ __forceinline__ u16 f2bf(float x) {
    union { float f; uint32_t u; } v; v.f = x;
    uint32_t r = v.u + 0x7fffu + ((v.u >> 16) & 1u);   // RNE
    return (u16)(r >> 16);
}

__device__ __forceinline__ void async16(const u16* g, u16* l) {
    __builtin_amdgcn_global_load_lds((__attribute__((address_space(1))) void*)(g),
                                     (__attribute__((address_space(3))) void*)(l),
                                     16, 0, 0);
}

// ---------- bf16 MFMA GEMM with K-split:
//   Cpart[split][M x BN] = A[M x kslice] @ W[kslice x BN]
// A: fp32 row-major (lda = K), converted to bf16 during LDS staging.
// Bt: pre-converted tiled weights: [KT][BN][32] bf16 (zero-padded in K).
// grid.y = split index; kt range [kt0 + y*ktPer, min(kt0+(y+1)*ktPer, KT)).

template<int BM, int BN, int WM, int WN>
__global__ __launch_bounds__((BM/WM)*(BN/WN)*64)
void gemm_xw(const float* __restrict__ A, const u16* __restrict__ Bt,
             float* __restrict__ C, int M, int K, int KT, int ktPer)
{
    constexpr int WAVES   = (BM/WM)*(BN/WN);
    constexpr int THREADS = WAVES*64;
    constexpr int RF = WM/16, CF = WN/16;
    constexpr int BCH = (BN*64)/(16*THREADS);     // 16B chunks of B per thread
    static_assert((BM*32)/THREADS == 8, "A staging assumes 8 floats per thread");

    __shared__ __align__(16) u16 As[BM*32];
    __shared__ __align__(16) u16 Bs[BN*32];

    const int tid  = threadIdx.x;
    const int wid  = tid >> 6, lane = tid & 63;
    const int quad = lane >> 4, l16 = lane & 15;
    constexpr int WCOLS = BN/WN;
    const int wm = (wid / WCOLS) * WM;
    const int wn = (wid % WCOLS) * WN;
    const long m0 = (long)blockIdx.x * BM;

    const int ktA = blockIdx.y * ktPer;
    const int ktB = min(ktA + ktPer, KT);
    float* Cp = C + (size_t)blockIdx.y * (size_t)M * BN;

    const int arow = tid >> 2;            // 4 threads cover one row's 32 k
    const int akk  = (tid & 3) * 8;
    const bool aok = (m0 + arow) < M;
    const float* aptr = A + (size_t)(m0 + arow) * K + akk;

    f4 acc[RF][CF];
    #pragma unroll
    for (int r = 0; r < RF; ++r)
        #pragma unroll
        for (int c = 0; c < CF; ++c)
            #pragma unroll
            for (int g = 0; g < 4; ++g) acc[r][c][g] = 0.f;

    const u16* Asl = As + (wm + l16)*32 + quad*8;
    const u16* Bsl = Bs + (wn + l16)*32 + quad*8;

    for (int kt = ktA; kt < ktB; ++kt) {
        __syncthreads();
        #pragma unroll
        for (int i = 0; i < BCH; ++i) {
            int c16 = i*THREADS + tid;
            async16(Bt + (size_t)kt*(BN*32) + (size_t)c16*8, (u16*)Bs + c16*8);
        }
        {
            const int gk = kt*32 + akk;
            f4 v0, v1;
            #pragma unroll
            for (int g = 0; g < 4; ++g) { v0[g] = 0.f; v1[g] = 0.f; }
            if (aok && gk < K) {
                const float* p = aptr + (size_t)kt*32;
                v0 = *(const f4*)p;
                v1 = *(const f4*)(p + 4);
            }
            short8 w;
            #pragma unroll
            for (int g = 0; g < 4; ++g) {
                w[g]   = (short)f2bf(v0[g]);
                w[4+g] = (short)f2bf(v1[g]);
            }
            *(short8*)(As + tid*8) = w;
        }
        __syncthreads();

        short8 af[RF], bfr[CF];
        #pragma unroll
        for (int r = 0; r < RF; ++r) af[r]  = *(const short8*)(Asl + r*16*32);
        #pragma unroll
        for (int c = 0; c < CF; ++c) bfr[c] = *(const short8*)(Bsl + c*16*32);
        #pragma unroll
        for (int r = 0; r < RF; ++r)
            #pragma unroll
            for (int c = 0; c < CF; ++c)
                acc[r][c] = __builtin_amdgcn_mfma_f32_16x16x32_bf16(af[r], bfr[c], acc[r][c], 0, 0, 0);
    }

    // epilogue: D[m=quad*4+g][n=l16]
    #pragma unroll
    for (int r = 0; r < RF; ++r) {
        const long rb = m0 + wm + r*16 + quad*4;
        #pragma unroll
        for (int c = 0; c < CF; ++c) {
            const int col = wn + c*16 + l16;
            #pragma unroll
            for (int g = 0; g < 4; ++g) {
                long row = rb + g;
                if (row < M) Cp[row*(long)BN + col] = acc[r][c][g];
            }
        }
    }
}

// ---------- split-K reduce + attention scores (layer-1 epilogue) ----------
// wave per node; lane covers col = lane*4 .. lane*4+3 of the 256-wide row.
// Sums S partial buffers, writes h, computes es/ed per head (16-lane groups).
__global__ void k_reduce_scores(const float* __restrict__ parts, size_t partStride, int S,
                                const float* __restrict__ asrc, const float* __restrict__ adst,
                                float* __restrict__ h, float* __restrict__ es,
                                float* __restrict__ ed, int N)
{
    int wave = threadIdx.x >> 6, lane = threadIdx.x & 63;
    int node = blockIdx.x*4 + wave;
    if (node >= N) return;
    size_t base = (size_t)node*256 + lane*4;
    f4 v;
    #pragma unroll
    for (int g = 0; g < 4; ++g) v[g] = 0.f;
    for (int s = 0; s < S; ++s) {
        f4 p = *(const f4*)(parts + s*partStride + base);
        #pragma unroll
        for (int g = 0; g < 4; ++g) v[g] += p[g];
    }
    *(f4*)(h + base) = v;

    int hh = lane >> 4;                 // head
    int c0 = (lane & 15) * 4;           // col within head
    float s = 0.f, d = 0.f;
    #pragma unroll
    for (int g = 0; g < 4; ++g) {
        s += v[g] * asrc[hh*64 + c0 + g];
        d += v[g] * adst[hh*64 + c0 + g];
    }
    #pragma unroll
    for (int off = 1; off < 16; off <<= 1) {
        s += __shfl_xor(s, off);
        d += __shfl_xor(d, off);
    }
    if ((lane & 15) == 0) { es[node*4 + hh] = s; ed[node*4 + hh] = d; }
}

// ---------- weight prep: W[K x Nn] fp32 -> Bt[KT][Nn][32] bf16, zero-pad K ----------
__global__ void k_prep_w(const float* __restrict__ W, u16* __restrict__ out,
                         int K, int Nn, int total)
{
    int idx = blockIdx.x*256 + threadIdx.x;
    if (idx >= total) return;
    int ki = idx & 31;
    int rest = idx >> 5;
    int nn = rest % Nn;
    int kt = rest / Nn;
    int k = kt*32 + ki;
    float v = (k < K) ? W[(size_t)k*Nn + nn] : 0.f;
    out[idx] = f2bf(v);
}

// ---------- CSR build ----------
__global__ void k_hist(const int* __restrict__ ei, int E, int N, int* counts)
{
    int i = blockIdx.x*256 + threadIdx.x;
    if (i >= E + N) return;
    int d = (i < E) ? ei[E + i] : (i - E);   // self-loop tail
    atomicAdd(&counts[d], 1);
}

__global__ void k_scan1(const int* __restrict__ counts, int* offs, int* partials, int N)
{
    __shared__ int s[256];
    int i = blockIdx.x*256 + threadIdx.x;
    int v = (i < N) ? counts[i] : 0;
    s[threadIdx.x] = v;
    __syncthreads();
    #pragma unroll
    for (int off = 1; off < 256; off <<= 1) {
        int t = (threadIdx.x >= off) ? s[threadIdx.x - off] : 0;
        __syncthreads();
        s[threadIdx.x] += t;
        __syncthreads();
    }
    if (i < N) offs[i + 1] = s[threadIdx.x];
    if (threadIdx.x == 255) partials[blockIdx.x] = s[255];
    if (i == 0) offs[0] = 0;
}

__global__ void k_scan2(int* partials, int NB)
{
    __shared__ int s[256];
    int v = (threadIdx.x < NB) ? partials[threadIdx.x] : 0;
    s[threadIdx.x] = v;
    __syncthreads();
    for (int off = 1; off < 256; off <<= 1) {
        int t = (threadIdx.x >= off) ? s[threadIdx.x - off] : 0;
        __syncthreads();
        s[threadIdx.x] += t;
        __syncthreads();
    }
    if (threadIdx.x < NB) partials[threadIdx.x] = s[threadIdx.x] - v;  // exclusive
}

__global__ void k_scan3(int* offs, const int* __restrict__ partials, int N)
{
    int i = blockIdx.x*256 + threadIdx.x;
    if (i < N) offs[i + 1] += partials[blockIdx.x];
}

__global__ void k_copy(const int* __restrict__ a, int* __restrict__ b, int n)
{
    int i = blockIdx.x*256 + threadIdx.x;
    if (i < n) b[i] = a[i];
}

__global__ void k_scatter(const int* __restrict__ ei, int E, int N,
                          int* cursor, int* __restrict__ ssrc)
{
    int i = blockIdx.x*256 + threadIdx.x;
    if (i >= E + N) return;
    int s, d;
    if (i < E) { s = ei[i]; d = ei[E + i]; } else { s = i - E; d = s; }
    int pos = atomicAdd(&cursor[d], 1);
    ssrc[pos] = s;
}

// ---------- per-node attention logits (layers 2,3) ----------
__global__ void k_scores(const float* __restrict__ h, const float* __restrict__ asrc,
                         const float* __restrict__ adst, float* __restrict__ es,
                         float* __restrict__ ed, int N, int H)
{
    int wave = threadIdx.x >> 6, lane = threadIdx.x & 63;
    int node = blockIdx.x*4 + wave;
    if (node >= N) return;
    const float* row = h + (size_t)node * H * 64;
    for (int hh = 0; hh < H; ++hh) {
        float v = row[hh*64 + lane];
        float s = v * asrc[hh*64 + lane];
        float d = v * adst[hh*64 + lane];
        #pragma unroll
        for (int off = 32; off > 0; off >>= 1) {
            s += __shfl_down(s, off);
            d += __shfl_down(d, off);
        }
        if (lane == 0) { es[node*H + hh] = s; ed[node*H + hh] = d; }
    }
}

// ---------- online-softmax aggregation + bias + ELU ----------
// block per node, wave per head, lane = feature. Single pass over edges:
// running max m, rescaled denom l, rescaled feature accumulator acc.
__global__ void k_agg(const float* __restrict__ h, const int* __restrict__ offs,
                      const int* __restrict__ ssrc, const float* __restrict__ es,
                      const float* __restrict__ ed, const float* __restrict__ bias,
                      float* __restrict__ out, int N, int H)
{
    int n = blockIdx.x;
    int hh = threadIdx.x >> 6, lane = threadIdx.x & 63;
    int s0 = offs[n], s1 = offs[n + 1];
    float edv = ed[n*H + hh];
    float m = -1e30f, l = 0.f, acc = 0.f;
    const int stride = H*64;
    for (int j = s0; j < s1; ++j) {
        int sidx = ssrc[j];
        float e = es[sidx*H + hh] + edv;
        e = (e > 0.f) ? e : 0.2f*e;
        if (e > m) {                       // wave-uniform branch
            float sc = __expf(m - e);
            l *= sc; acc *= sc; m = e;
        }
        float p = __expf(e - m);
        l += p;
        acc += p * h[(size_t)sidx*stride + hh*64 + lane];
    }
    float v = acc / l + bias[hh*64 + lane];
    out[(size_t)n*stride + hh*64 + lane] = (v > 0.f) ? v : (__expf(v) - 1.f);
}

// ---------- classifier: out[N x 3] = h[N x 64] @ Wc[64 x 3] + bc ----------
__global__ void k_classifier(const float* __restrict__ h, const float* __restrict__ Wc,
                             const float* __restrict__ bc, float* __restrict__ out, int N)
{
    __shared__ float wc[192];
    __shared__ float bcs[3];
    if (threadIdx.x < 192) wc[threadIdx.x] = Wc[threadIdx.x];
    if (threadIdx.x < 3)   bcs[threadIdx.x] = bc[threadIdx.x];
    __syncthreads();
    int n = blockIdx.x*blockDim.x + threadIdx.x;
    if (n >= N) return;
    const float4* row = (const float4*)(h + (size_t)n*64);
    float a0 = 0.f, a1 = 0.f, a2 = 0.f;
    #pragma unroll
    for (int q = 0; q < 16; ++q) {
        float4 v = row[q];
        const float* w = &wc[q*12];
        a0 += v.x*w[0] + v.y*w[3] + v.z*w[6] + v.w*w[9];
        a1 += v.x*w[1] + v.y*w[4] + v.z*w[7] + v.w*w[10];
        a2 += v.x*w[2] + v.y*w[5] + v.z*w[8] + v.w*w[11];
    }
    out[n*3 + 0] = a0 + bcs[0];
    out[n*3 + 1] = a1 + bcs[1];
    out[n*3 + 2] = a2 + bcs[2];
}

// ---------- launcher ----------
extern "C" void kernel_launch(void* const* d_in, const int* in_sizes, int n_in,
                              void* d_out, int out_size, void* d_ws, size_t ws_size,
                              hipStream_t stream)
{
    const float* x   = (const float*)d_in[0];
    const float* W1  = (const float*)d_in[1];
    const float* a1s = (const float*)d_in[2];
    const float* a1d = (const float*)d_in[3];
    const float* b1  = (const float*)d_in[4];
    const float* W2  = (const float*)d_in[5];
    const float* a2s = (const float*)d_in[6];
    const float* a2d = (const float*)d_in[7];
    const float* b2  = (const float*)d_in[8];
    const float* W3  = (const float*)d_in[9];
    const float* a3s = (const float*)d_in[10];
    const float* a3d = (const float*)d_in[11];
    const float* b3  = (const float*)d_in[12];
    const float* Wc  = (const float*)d_in[13];
    const float* bc  = (const float*)d_in[14];
    const int*   ei  = (const int*)d_in[15];
    float* out = (float*)d_out;

    const int DIN = in_sizes[1] / 256;    // 5000
    const int N   = in_sizes[0] / DIN;    // 30000
    const int E   = in_sizes[15] / 2;     // 480000
    const int KT1 = (DIN + 31) / 32;      // 157
    const int ET  = E + N;
    const int SPLITS = 4;
    const int KTP = (KT1 + SPLITS - 1) / SPLITS;   // 40

    char* ws = (char*)d_ws;
    size_t off = 0;
    auto alloc = [&](size_t bytes) -> void* {
        void* p = ws + off;
        off += (bytes + 255) & ~(size_t)255;
        return p;
    };

    float* bufA   = (float*)alloc((size_t)N*256*4);
    float* bufB   = (float*)alloc((size_t)N*256*4);
    float* bufP   = (float*)alloc((size_t)SPLITS*N*256*4);  // split-K partials
    u16*  Wt1     = (u16*)alloc((size_t)KT1*256*32*2);
    u16*  Wt2     = (u16*)alloc((size_t)8*256*32*2);
    u16*  Wt3     = (u16*)alloc((size_t)8*64*32*2);
    float* es     = (float*)alloc((size_t)N*4*4);
    float* ed     = (float*)alloc((size_t)N*4*4);
    int* counts   = (int*)alloc((size_t)N*4);
    int* offs     = (int*)alloc((size_t)(N+1)*4);
    int* cursor   = (int*)alloc((size_t)N*4);
    int* partials = (int*)alloc(1024);
    int* ssrc     = (int*)alloc((size_t)ET*4);

    const int NB = (N + 255)/256;
    const int GM = (N + 63)/64;

    // CSR over (edges + self-loops); graph identical across the 3 layers
    hipMemsetAsync(counts, 0, (size_t)N*4, stream);
    k_hist   <<<(ET+255)/256, 256, 0, stream>>>(ei, E, N, counts);
    k_scan1  <<<NB, 256, 0, stream>>>(counts, offs, partials, N);
    k_scan2  <<<1, 256, 0, stream>>>(partials, NB);
    k_scan3  <<<NB, 256, 0, stream>>>(offs, partials, N);
    k_copy   <<<NB, 256, 0, stream>>>(offs, cursor, N);
    k_scatter<<<(ET+255)/256, 256, 0, stream>>>(ei, E, N, cursor, ssrc);

    // weights -> bf16 tiled
    k_prep_w<<<(KT1*256*32+255)/256, 256, 0, stream>>>(W1, Wt1, DIN, 256, KT1*256*32);
    k_prep_w<<<(8*256*32+255)/256, 256, 0, stream>>>(W2, Wt2, 256, 256, 8*256*32);
    k_prep_w<<<(8*64*32+255)/256, 256, 0, stream>>>(W3, Wt3, 256, 64, 8*64*32);

    // layer 1: split-K GEMM -> fused reduce+scores -> online agg
    gemm_xw<64,256,64,64><<<dim3(GM, SPLITS), 256, 0, stream>>>(x, Wt1, bufP, N, DIN, KT1, KTP);
    k_reduce_scores<<<(N+3)/4, 256, 0, stream>>>(bufP, (size_t)N*256, SPLITS, a1s, a1d,
                                                 bufA, es, ed, N);
    k_agg   <<<N, 256, 0, stream>>>(bufA, offs, ssrc, es, ed, b1, bufB, N, 4);
    // layer 2
    gemm_xw<64,256,64,64><<<dim3(GM, 1), 256, 0, stream>>>(bufB, Wt2, bufA, N, 256, 8, 8);
    k_scores<<<(N+3)/4, 256, 0, stream>>>(bufA, a2s, a2d, es, ed, N, 4);
    k_agg   <<<N, 256, 0, stream>>>(bufA, offs, ssrc, es, ed, b2, bufB, N, 4);
    // layer 3 (1 head)
    gemm_xw<64,64,16,64><<<dim3(GM, 1), 256, 0, stream>>>(bufB, Wt3, bufA, N, 256, 8, 8);
    k_scores<<<(N+3)/4, 256, 0, stream>>>(bufA, a3s, a3d, es, ed, N, 1);
    k_agg   <<<N, 64, 0, stream>>>(bufA, offs, ssrc, es, ed, b3, bufB, N, 1);
    // classifier
    k_classifier<<<(N+255)/256, 256, 0, stream>>>(bufB, Wc, bc, out, N);
}